// Round 6
// baseline (110.579 us; speedup 1.0000x reference)
//
#include <hip/hip_runtime.h>

// Problem constants
#define D_B 8
#define N_T 2048
#define NN  64
#define N_H 8
#define N_C 32   // u-chunks of 64
#define NP  72   // padded LDS row stride (bf16): 144 B rows -> 2-way bank alias (free)

typedef __bf16 bf16;
typedef bf16 bf16x8 __attribute__((ext_vector_type(8)));
typedef bf16 bf16x4 __attribute__((ext_vector_type(4)));
typedef float f32x4 __attribute__((ext_vector_type(4)));

static __device__ __forceinline__ f32x4 mfma16(bf16x8 a, bf16x8 b, f32x4 c) {
    // a_frag[j] = A[lane&15][(lane>>4)*8+j]; b_frag[j] = B[(lane>>4)*8+j][lane&15]
    // d[r] = D[(lane>>4)*4+r][lane&15]
    return __builtin_amdgcn_mfma_f32_16x16x32_bf16(a, b, c, 0, 0, 0);
}

static __device__ __forceinline__ bf16x8 ldcvt8(const float* p) {
    const f32x4 v0 = *(const f32x4*)p;
    const f32x4 v1 = *(const f32x4*)(p + 4);
    bf16x8 r;
#pragma unroll
    for (int k = 0; k < 4; k++) { r[k] = (bf16)v0[k]; r[4 + k] = (bf16)v1[k]; }
    return r;
}

// ---------------------------------------------------------------------------
// K1: block (b, c, qt) handles heads {4qt..4qt+3} of chunk c:
//   Qrd[b,c,h][u][i'] (via LDS bounce, coalesced flush)
//   Erd[b,c,h][i][u]  (transposed, coalesced flush)
//   dGq[b,c,qt][i][i'] = sum_{h in half} sum_u Qr[u,i'] Er[u,i]  (bf16)
//   Rbf (qt==0 only).
// Grid (D_B, N_C, 2): linear%8 = b -> per-batch XCD L2 locality.
// 55.3 KB LDS, 2 blocks/CU (8 waves/CU).
// ---------------------------------------------------------------------------
__global__ __launch_bounds__(256, 2) void k_dg(
    const float* __restrict__ rp, const float* __restrict__ Qm,
    const float* __restrict__ Em,
    bf16* __restrict__ dGq, bf16* __restrict__ Rbf,
    bf16* __restrict__ Qrd, bf16* __restrict__ Erd)
{
    __shared__ bf16 Rl[64 * NP];   // R chunk [u][j]
    __shared__ bf16 Ql[64 * NP];   // Q_h [i'][j]
    __shared__ bf16 El[64 * NP];   // E_h [i][j]
    __shared__ bf16 QT[64 * NP];   // Qr tile [i'][u] (dG A-operand; dG staging at tail)
    __shared__ bf16 ET[64 * NP];   // Er tile [i][u]
    __shared__ bf16 QU[64 * NP];   // Qr tile [u][i'] (global-flush layout)
    const int b = blockIdx.x, c = blockIdx.y, qt = blockIdx.z;
    const int tid = threadIdx.x;
    const int w = tid >> 6, l = tid & 63, q = l >> 4, l16 = l & 15;
    const int row = tid >> 2, col = (tid & 3) * 16;

    {
        const float* src = rp + ((size_t)b * N_T + c * 64 + row) * NN + col;
        const bf16x8 v0 = ldcvt8(src), v1 = ldcvt8(src + 8);
        *(bf16x8*)&Rl[row * NP + col] = v0;
        *(bf16x8*)&Rl[row * NP + col + 8] = v1;
        if (qt == 0) {
            bf16* d = Rbf + ((size_t)b * N_T + c * 64 + row) * NN + col;
            *(bf16x8*)d = v0;
            *(bf16x8*)(d + 8) = v1;
        }
    }
    __syncthreads();
    const bf16x8 a0 = *(const bf16x8*)&Rl[(w * 16 + l16) * NP + q * 8];
    const bf16x8 a1 = *(const bf16x8*)&Rl[(w * 16 + l16) * NP + 32 + q * 8];

    f32x4 dacc[4];
#pragma unroll
    for (int ns = 0; ns < 4; ns++) { f32x4 z = {0.f, 0.f, 0.f, 0.f}; dacc[ns] = z; }

    for (int hh = 0; hh < 4; hh++) {
        const int h = qt * 4 + hh;
        // stage Q_h/E_h fp32 -> bf16 LDS (coalesced; L2-resident after 1st touch)
        {
            const float* qs = Qm + (size_t)h * 4096 + row * 64 + col;
            const float* es = Em + (size_t)h * 4096 + row * 64 + col;
            *(bf16x8*)&Ql[row * NP + col]     = ldcvt8(qs);
            *(bf16x8*)&Ql[row * NP + col + 8] = ldcvt8(qs + 8);
            *(bf16x8*)&El[row * NP + col]     = ldcvt8(es);
            *(bf16x8*)&El[row * NP + col + 8] = ldcvt8(es + 8);
        }
        __syncthreads();
        const size_t tb = (((size_t)(b * N_C + c)) * N_H + h) * 4096;
#pragma unroll
        for (int ns = 0; ns < 4; ns++) {
            // Qr[u,i'] : B storage [n=i'][k=j] = Ql
            bf16x8 b0 = *(const bf16x8*)&Ql[(ns * 16 + l16) * NP + q * 8];
            bf16x8 b1 = *(const bf16x8*)&Ql[(ns * 16 + l16) * NP + 32 + q * 8];
            f32x4 z = {0.f, 0.f, 0.f, 0.f};
            f32x4 s = mfma16(a0, b0, z);
            s = mfma16(a1, b1, s);
            bf16x4 p;
#pragma unroll
            for (int r = 0; r < 4; r++) p[r] = (bf16)s[r];
            *(bf16x4*)&QT[(ns * 16 + l16) * NP + w * 16 + q * 4] = p;   // [i'][u]
#pragma unroll
            for (int r = 0; r < 4; r++)                                  // [u][i']
                QU[(w * 16 + q * 4 + r) * NP + ns * 16 + l16] = p[r];
            // Er[u,i]
            b0 = *(const bf16x8*)&El[(ns * 16 + l16) * NP + q * 8];
            b1 = *(const bf16x8*)&El[(ns * 16 + l16) * NP + 32 + q * 8];
            f32x4 s2 = mfma16(a0, b0, z);
            s2 = mfma16(a1, b1, s2);
#pragma unroll
            for (int r = 0; r < 4; r++) p[r] = (bf16)s2[r];
            *(bf16x4*)&ET[(ns * 16 + l16) * NP + w * 16 + q * 4] = p;   // [i][u]
        }
        __syncthreads();
        // dG[i'][i] += Qr^T Er : A from QT [i'][u], B from ET [i][u]
        {
            const bf16x8 qa0 = *(const bf16x8*)&QT[(w * 16 + l16) * NP + q * 8];
            const bf16x8 qa1 = *(const bf16x8*)&QT[(w * 16 + l16) * NP + 32 + q * 8];
#pragma unroll
            for (int ns = 0; ns < 4; ns++) {
                const bf16x8 e0 = *(const bf16x8*)&ET[(ns * 16 + l16) * NP + q * 8];
                const bf16x8 e1 = *(const bf16x8*)&ET[(ns * 16 + l16) * NP + 32 + q * 8];
                dacc[ns] = mfma16(qa0, e0, dacc[ns]);
                dacc[ns] = mfma16(qa1, e1, dacc[ns]);
            }
        }
        // coalesced flushes: Erd from ET, Qrd from QU (8 KB each)
        {
            bf16* de = Erd + tb + row * 64 + col;
            *(bf16x8*)de       = *(const bf16x8*)&ET[row * NP + col];
            *(bf16x8*)(de + 8) = *(const bf16x8*)&ET[row * NP + col + 8];
            bf16* dq = Qrd + tb + row * 64 + col;
            *(bf16x8*)dq       = *(const bf16x8*)&QU[row * NP + col];
            *(bf16x8*)(dq + 8) = *(const bf16x8*)&QU[row * NP + col + 8];
        }
        __syncthreads();   // all QT/ET/QU/Ql/El reads done before next head
    }
    // transpose dacc (D row=i', col=i) -> QT as [i][i'], coalesced store
#pragma unroll
    for (int ns = 0; ns < 4; ns++) {
        bf16x4 p;
#pragma unroll
        for (int r = 0; r < 4; r++) p[r] = (bf16)dacc[ns][r];
        *(bf16x4*)&QT[(ns * 16 + l16) * NP + w * 16 + q * 4] = p;
    }
    __syncthreads();
    {
        bf16* dst = dGq + (((size_t)(b * N_C + c)) * 2 + qt) * 4096 + row * 64 + col;
        *(bf16x8*)dst       = *(const bf16x8*)&QT[row * NP + col];
        *(bf16x8*)(dst + 8) = *(const bf16x8*)&QT[row * NP + col + 8];
    }
}

// ---------------------------------------------------------------------------
// K2: block (b, c, half) computes out rows [c*64 + half*32, +32):
//   inline scan of dGq halves -> Gb; barrier-free head loop with per-wave
//   private S slabs; half=0 skips masked-out upper u-range.
// Grid (D_B, N_C, 2): linear%8 = b; 512 blocks, 2+ blocks/CU.
// ---------------------------------------------------------------------------
__global__ __launch_bounds__(256, 4) void k_out(
    const bf16* __restrict__ dGq, const bf16* __restrict__ Rbf,
    const bf16* __restrict__ Qrd, const bf16* __restrict__ Erd,
    float* __restrict__ out)
{
    __shared__ bf16 Gb[64 * NP];      // Gcum [i][i']
    __shared__ bf16 Sl[4 * 16 * NP];  // per-wave S slabs
    __shared__ float Ob[32 * 65];     // h-group reduction
    const int b = blockIdx.x, c = blockIdx.y, half = blockIdx.z;
    const int tid = threadIdx.x;
    const int w = tid >> 6, l = tid & 63, q = l >> 4, l16 = l & 15;
    const int s = w & 1, g = w >> 1;

    // ---- inline exclusive scan over dGq halves (<=62 x 16B per thread)
    {
        float run[16];
#pragma unroll
        for (int k = 0; k < 16; k++) run[k] = 0.f;
        const bf16* base = dGq + (size_t)b * N_C * 2 * 4096 + tid * 16;
        for (int t = 0; t < 2 * c; t++) {
            const bf16x8 v0 = *(const bf16x8*)(base + (size_t)t * 4096);
            const bf16x8 v1 = *(const bf16x8*)(base + (size_t)t * 4096 + 8);
#pragma unroll
            for (int k = 0; k < 8; k++) { run[k] += (float)v0[k]; run[8 + k] += (float)v1[k]; }
        }
        // elem idx = tid*16+k -> i = tid>>2, i' = (tid&3)*16 + k
        bf16x8 o0, o1;
#pragma unroll
        for (int k = 0; k < 8; k++) { o0[k] = (bf16)run[k]; o1[k] = (bf16)run[8 + k]; }
        *(bf16x8*)&Gb[(tid >> 2) * NP + (tid & 3) * 16] = o0;
        *(bf16x8*)&Gb[(tid >> 2) * NP + (tid & 3) * 16 + 8] = o1;
    }
    __syncthreads();

    // A-frags: R rows t = c*64 + half*32 + s*16 + l16
    const int trow = c * 64 + half * 32 + s * 16 + l16;
    const bf16x8 ra0 = *(const bf16x8*)&Rbf[((size_t)b * N_T + trow) * NN + q * 8];
    const bf16x8 ra1 = *(const bf16x8*)&Rbf[((size_t)b * N_T + trow) * NN + 32 + q * 8];

    bf16* Sw = Sl + w * 16 * NP;
    const int NU = half ? 4 : 2;   // u-tiles needed under the causal mask
    f32x4 acc[4];
#pragma unroll
    for (int ns = 0; ns < 4; ns++) { f32x4 z = {0.f, 0.f, 0.f, 0.f}; acc[ns] = z; }

    for (int hh = 0; hh < 4; hh++) {
        const int h = g * 4 + hh;
        const bf16* Qh = Qrd + (((size_t)(b * N_C + c)) * N_H + h) * 4096;  // [u][i']
        const bf16* Eh = Erd + (((size_t)(b * N_C + c)) * N_H + h) * 4096;  // [i][u]
        // S[t][u] = sum_i' R[t,i'] Qr[u,i'], masked -> per-wave slab
        for (int nu = 0; nu < NU; nu++) {
            const bf16x8 b0 = *(const bf16x8*)&Qh[(nu * 16 + l16) * 64 + q * 8];
            const bf16x8 b1 = *(const bf16x8*)&Qh[(nu * 16 + l16) * 64 + 32 + q * 8];
            f32x4 z = {0.f, 0.f, 0.f, 0.f};
            f32x4 sv = mfma16(ra0, b0, z);
            sv = mfma16(ra1, b1, sv);
            const int u_loc = nu * 16 + l16;
#pragma unroll
            for (int r = 0; r < 4; r++) {
                const int t_loc = half * 32 + s * 16 + q * 4 + r;
                Sw[(q * 4 + r) * NP + u_loc] = (u_loc <= t_loc) ? (bf16)sv[r] : (bf16)0.f;
            }
        }
        // same-wave LDS RAW (in-order DS per wave); S back as A-operand
        const bf16x8 sa0 = *(const bf16x8*)&Sw[l16 * NP + q * 8];
#pragma unroll
        for (int ns = 0; ns < 4; ns++) {
            const bf16x8 e0 = *(const bf16x8*)&Eh[(ns * 16 + l16) * 64 + q * 8];
            acc[ns] = mfma16(sa0, e0, acc[ns]);
        }
        if (half) {
            const bf16x8 sa1 = *(const bf16x8*)&Sw[l16 * NP + 32 + q * 8];
#pragma unroll
            for (int ns = 0; ns < 4; ns++) {
                const bf16x8 e1 = *(const bf16x8*)&Eh[(ns * 16 + l16) * 64 + 32 + q * 8];
                acc[ns] = mfma16(sa1, e1, acc[ns]);
            }
        }
    }
    // prefix term (g==1): O += R_t * Gcum, B storage [n=i][k=i'] = Gb
    if (g == 1) {
#pragma unroll
        for (int ns = 0; ns < 4; ns++) {
            const bf16x8 g0 = *(const bf16x8*)&Gb[(ns * 16 + l16) * NP + q * 8];
            const bf16x8 g1 = *(const bf16x8*)&Gb[(ns * 16 + l16) * NP + 32 + q * 8];
            acc[ns] = mfma16(ra0, g0, acc[ns]);
            acc[ns] = mfma16(ra1, g1, acc[ns]);
        }
    }
    if (g == 0) {
#pragma unroll
        for (int ns = 0; ns < 4; ns++)
#pragma unroll
            for (int r = 0; r < 4; r++)
                Ob[(s * 16 + q * 4 + r) * 65 + ns * 16 + l16] = acc[ns][r];
    }
    __syncthreads();
    if (g == 1) {
        const int t0 = c * 64 + half * 32;
#pragma unroll
        for (int ns = 0; ns < 4; ns++)
#pragma unroll
            for (int r = 0; r < 4; r++) {
                const float sum = acc[ns][r] + Ob[(s * 16 + q * 4 + r) * 65 + ns * 16 + l16];
                out[((size_t)b * N_T + t0 + s * 16 + q * 4 + r) * NN + ns * 16 + l16] = sum;
            }
    }
}

// ---------------------------------------------------------------------------
extern "C" void kernel_launch(void* const* d_in, const int* in_sizes, int n_in,
                              void* d_out, int out_size, void* d_ws, size_t ws_size,
                              hipStream_t stream) {
    const float* rp = (const float*)d_in[0];   // (8, 2048, 64) fp32
    const float* Qm = (const float*)d_in[1];   // (8, 64, 64)
    const float* Em = (const float*)d_in[2];   // (8, 64, 64)
    float* out = (float*)d_out;                // (8, 2048, 64) fp32

    // ws: dGq 4.2 MB + Rbf 2 MB + Qrd 16.8 MB + Erd 16.8 MB  (~40 MB)
    bf16* dGq = (bf16*)d_ws;
    bf16* Rbf = dGq + (size_t)D_B * N_C * 2 * 4096;
    bf16* Qrd = Rbf + (size_t)D_B * N_T * NN;
    bf16* Erd = Qrd + (size_t)D_B * N_C * N_H * 4096;

    k_dg<<<dim3(D_B, N_C, 2), 256, 0, stream>>>(rp, Qm, Em, dGq, Rbf, Qrd, Erd);
    k_out<<<dim3(D_B, N_C, 2), 256, 0, stream>>>(dGq, Rbf, Qrd, Erd, out);
}